// Round 6
// baseline (524.389 us; speedup 1.0000x reference)
//
#include <hip/hip_runtime.h>

// TimeFeatureEmbedding: y[b,t,d] = sum_e x[b,t,e]*W[d,e] + b[d], broadcast
// to [B,T,S,D]. D=512, d_inp=4, S=64. Output 402.65 MB fp32 -> pure
// store-BW-bound. Floor = 402.65MB / 6.3 TB/s ~= 64 us.
//
// Dead theories (all ~neutral): R1 vmcnt load/store coupling (LDS staging),
// R3 L2 write-allocate (nt stores), R4 concurrency (2048->256 blocks gave
// only ~-17us, and fillBuffer uses ~820 waves vs our 1024 -- same stream
// count, 2.2x the BW -> desync can't be the cause).
//
// R6 = R5 resubmitted (R5 failed on container infra, no data). MEASUREMENT
// round. Ambiguity: dur_us decomposition relies on "one ~256us fill inside
// the timed region"; if a second ~63us fill (402MB output poison, hidden
// below top-5) is also inside, the kernel is ALREADY ~75us ~= roofline.
// To resolve: this dispatch writes the output 3x (idempotent). If
// single-pass K~138us the dispatch (~414us) tops the rocprof table and
// exposes our kernel's own counters (FETCH_SIZE ~= WRITE would reveal
// read-for-ownership as the hidden 2x). If K~75us it stays hidden and
// dur_delta/2 pins K at the roofline -> done.

#define D_MODEL 512
#define D_INP   4

typedef float v4f __attribute__((ext_vector_type(4)));

__device__ __forceinline__ v4f tfe_row(const float4 xv, const float4 w0,
                                       const float4 w1, const float4 w2,
                                       const float4 w3, const float4 bv) {
    v4f y;
    y.x = fmaf(xv.x, w0.x, fmaf(xv.y, w0.y, fmaf(xv.z, w0.z, fmaf(xv.w, w0.w, bv.x))));
    y.y = fmaf(xv.x, w1.x, fmaf(xv.y, w1.y, fmaf(xv.z, w1.z, fmaf(xv.w, w1.w, bv.y))));
    y.z = fmaf(xv.x, w2.x, fmaf(xv.y, w2.y, fmaf(xv.z, w2.z, fmaf(xv.w, w2.w, bv.z))));
    y.w = fmaf(xv.x, w3.x, fmaf(xv.y, w3.y, fmaf(xv.z, w3.z, fmaf(xv.w, w3.w, bv.w))));
    return y;
}

// Flat grid-stride store kernel, LDS-staged x, nt stores, npass write-passes
// (npass>1 only for the R6 self-measurement; all passes write identical data).
__global__ __launch_bounds__(256) void tfe_flat_lds_nt(
    const float4* __restrict__ x4,   // [BT]   x rows as float4 (d_inp=4)
    const float4* __restrict__ W4,   // [512]  each W row is one float4
    const float4* __restrict__ b4,   // [128]  bias as float4
    v4f* __restrict__ out4,          // flat output as native float4
    int btShift, int niter, int npass)
{
    __shared__ float4 xs[1536];      // 24 KB; niter<=1536 (=384 for S=64,G=256)

    const size_t stride = (size_t)gridDim.x * blockDim.x;
    const size_t f = (size_t)blockIdx.x * blockDim.x + threadIdx.x;
    const int d4 = (int)(f & 127);                      // stride%128==0 -> const
    const int btStep = (int)(stride >> btShift);        // 8 at G=256
    const int bt0 = (int)(((size_t)blockIdx.x * blockDim.x) >> btShift); // block-uniform

    for (int j = (int)threadIdx.x; j < niter; j += (int)blockDim.x)
        xs[j] = x4[bt0 + btStep * j];

    const float4 w0 = W4[4 * d4 + 0];
    const float4 w1 = W4[4 * d4 + 1];
    const float4 w2 = W4[4 * d4 + 2];
    const float4 w3 = W4[4 * d4 + 3];
    const float4 bv = b4[d4];
    __syncthreads();

    for (int pass = 0; pass < npass; ++pass) {
        v4f* o = out4 + f;
        #pragma unroll 4
        for (int i = 0; i < niter; ++i, o += stride) {
            const v4f y = tfe_row(xs[i], w0, w1, w2, w3, bv);
            __builtin_nontemporal_store(y, o);
        }
    }
}

// Fallback: flat grid-stride with in-loop x load (any pow2 S shape).
__global__ __launch_bounds__(256) void tfe_flat(
    const float4* __restrict__ x4, const float4* __restrict__ W4,
    const float4* __restrict__ b4, v4f* __restrict__ out4,
    size_t N4, int btShift)
{
    const size_t stride = (size_t)gridDim.x * blockDim.x;
    size_t f = (size_t)blockIdx.x * blockDim.x + threadIdx.x;
    const int d4 = (int)(f & 127);

    const float4 w0 = W4[4 * d4 + 0];
    const float4 w1 = W4[4 * d4 + 1];
    const float4 w2 = W4[4 * d4 + 2];
    const float4 w3 = W4[4 * d4 + 3];
    const float4 bv = b4[d4];

    for (; f < N4; f += stride) {
        const int bt = (int)(f >> btShift);
        const v4f y = tfe_row(x4[bt], w0, w1, w2, w3, bv);
        __builtin_nontemporal_store(y, &out4[f]);
    }
}

// Fallback for non-pow2 S: block-per-(b,t) kernel.
__global__ __launch_bounds__(256) void tfe_embed_bcast(
    const float* __restrict__ x, const float* __restrict__ W,
    const float* __restrict__ bias, float* __restrict__ out, int S)
{
    const int bt = blockIdx.x;
    const int tid = threadIdx.x;
    const int d4 = tid & 127;
    const int shalf = tid >> 7;
    const float4 xv = ((const float4*)x)[bt];
    const float4* Wv = (const float4*)W;
    const float4 w0 = Wv[4 * d4 + 0];
    const float4 w1 = Wv[4 * d4 + 1];
    const float4 w2 = Wv[4 * d4 + 2];
    const float4 w3 = Wv[4 * d4 + 3];
    const float4 bv = ((const float4*)bias)[d4];
    const v4f y = tfe_row(xv, w0, w1, w2, w3, bv);
    v4f* orow = (v4f*)out + (size_t)bt * (size_t)S * 128;
    for (int si = shalf; si < S; si += 2)
        __builtin_nontemporal_store(y, &orow[(size_t)si * 128 + d4]);
}

extern "C" void kernel_launch(void* const* d_in, const int* in_sizes, int n_in,
                              void* d_out, int out_size, void* d_ws, size_t ws_size,
                              hipStream_t stream) {
    const float* x    = (const float*)d_in[0];   // [B,T,4] fp32
    const float* W    = (const float*)d_in[2];   // [512,4] fp32
    const float* bias = (const float*)d_in[3];   // [512]   fp32
    float* out        = (float*)d_out;

    const int BT = in_sizes[0] / D_INP;               // 3072 (sizes in elements)
    const int S  = out_size / (BT * D_MODEL);         // 64
    const size_t N4 = (size_t)out_size / 4;           // float4 count

    if ((S & (S - 1)) == 0) {
        // btShift = log2(S * 128): S=64 -> 13
        int btShift = 0, v = S * (D_MODEL / 4);
        while ((1 << (btShift + 1)) <= v) ++btShift;

        const int G = 256, B = 256;                   // 1 block/CU, 4 waves/CU
        const size_t stride = (size_t)G * B;          // 65536 float4 = 1 MB
        const size_t row = (size_t)S * (D_MODEL / 4); // float4 per bt (8192)
        const size_t niter = (stride && N4 >= stride) ? N4 / stride : 0;

        if (niter >= 1 && niter <= 1536 &&
            (N4 % stride) == 0 &&                     // all threads run niter iters
            (stride % row) == 0 &&                    // (s,d4) invariant, btStep exact
            (row % (size_t)B) == 0) {                 // bt0 block-uniform
            // R6 MEASUREMENT: npass=3 (idempotent re-writes) to surface this
            // dispatch above the ~256us fills in the rocprof table.
            tfe_flat_lds_nt<<<G, B, 0, stream>>>(
                (const float4*)x, (const float4*)W, (const float4*)bias,
                (v4f*)out, btShift, (int)niter, 3);
        } else {
            tfe_flat<<<2048, B, 0, stream>>>(
                (const float4*)x, (const float4*)W, (const float4*)bias,
                (v4f*)out, N4, btShift);
        }
    } else {
        tfe_embed_bcast<<<BT, 256, 0, stream>>>(x, W, bias, out, S);
    }
}

// Round 7
// 393.759 us; speedup vs baseline: 1.3318x; 1.3318x over previous
//
#include <hip/hip_runtime.h>

// TimeFeatureEmbedding: y[b,t,d] = sum_e x[b,t,e]*W[d,e] + b[d], broadcast
// to [B,T,S,D]. D=512, d_inp=4, S=64. Output 402.65 MB fp32 -> pure
// store-BW-bound. Floor = 402.65MB / 6.3 TB/s ~= 64 us.
//
// FINAL ANALYSIS (R6 measurement round, npass=3 idempotent triple-write):
//   marginal pass cost = (524.4 - 394.8)/2 = 64.8 us = 6.21 TB/s
//   -> the store loop ALREADY streams at the fillBuffer ceiling.
//   dur_us ~395 decomposes as: kernel ~70us (~90% of store ceiling)
//   + ~255us harness big-poison fill + ~64us output-poison fill, both
//   inside the timed region and untouchable. Earlier rounds' "2.6 TB/s
//   kernel" was a decomposition error (fills double-counted as kernel).
// Dead theories (all ~neutral, as expected in hindsight): R1 vmcnt
// load/store coupling, R3 L2 write-allocate policy, R4 concurrency
// (2048->256 blocks: ~-17us, the only real kernel-side gain).
// Remaining headroom <= ~10us (~2.5% of dur_us) -> roofline.

#define D_MODEL 512
#define D_INP   4

typedef float v4f __attribute__((ext_vector_type(4)));

__device__ __forceinline__ v4f tfe_row(const float4 xv, const float4 w0,
                                       const float4 w1, const float4 w2,
                                       const float4 w3, const float4 bv) {
    v4f y;
    y.x = fmaf(xv.x, w0.x, fmaf(xv.y, w0.y, fmaf(xv.z, w0.z, fmaf(xv.w, w0.w, bv.x))));
    y.y = fmaf(xv.x, w1.x, fmaf(xv.y, w1.y, fmaf(xv.z, w1.z, fmaf(xv.w, w1.w, bv.y))));
    y.z = fmaf(xv.x, w2.x, fmaf(xv.y, w2.y, fmaf(xv.z, w2.z, fmaf(xv.w, w2.w, bv.z))));
    y.w = fmaf(xv.x, w3.x, fmaf(xv.y, w3.y, fmaf(xv.z, w3.z, fmaf(xv.w, w3.w, bv.w))));
    return y;
}

// Flat grid-stride store kernel, LDS-staged x, nt stores. Single pass.
// Preconditions (checked at launch): stride % (S*128) == 0 so (s,d4) and
// btStep are invariant; blockDim divides S*128 so bt0 is block-uniform;
// N4 % stride == 0 so all threads run exactly niter iterations.
__global__ __launch_bounds__(256) void tfe_flat_lds_nt(
    const float4* __restrict__ x4,   // [BT]   x rows as float4 (d_inp=4)
    const float4* __restrict__ W4,   // [512]  each W row is one float4
    const float4* __restrict__ b4,   // [128]  bias as float4
    v4f* __restrict__ out4,          // flat output as native float4
    int btShift, int niter)
{
    __shared__ float4 xs[1536];      // 24 KB; niter<=1536 (=384 for S=64,G=256)

    const size_t stride = (size_t)gridDim.x * blockDim.x;
    const size_t f = (size_t)blockIdx.x * blockDim.x + threadIdx.x;
    const int d4 = (int)(f & 127);                      // stride%128==0 -> const
    const int btStep = (int)(stride >> btShift);        // 8 at G=256
    const int bt0 = (int)(((size_t)blockIdx.x * blockDim.x) >> btShift); // block-uniform

    for (int j = (int)threadIdx.x; j < niter; j += (int)blockDim.x)
        xs[j] = x4[bt0 + btStep * j];

    const float4 w0 = W4[4 * d4 + 0];
    const float4 w1 = W4[4 * d4 + 1];
    const float4 w2 = W4[4 * d4 + 2];
    const float4 w3 = W4[4 * d4 + 3];
    const float4 bv = b4[d4];
    __syncthreads();

    v4f* o = out4 + f;
    #pragma unroll 4
    for (int i = 0; i < niter; ++i, o += stride) {
        const v4f y = tfe_row(xs[i], w0, w1, w2, w3, bv);
        __builtin_nontemporal_store(y, o);
    }
}

// Fallback: flat grid-stride with in-loop x load (any pow2 S shape).
__global__ __launch_bounds__(256) void tfe_flat(
    const float4* __restrict__ x4, const float4* __restrict__ W4,
    const float4* __restrict__ b4, v4f* __restrict__ out4,
    size_t N4, int btShift)
{
    const size_t stride = (size_t)gridDim.x * blockDim.x;
    size_t f = (size_t)blockIdx.x * blockDim.x + threadIdx.x;
    const int d4 = (int)(f & 127);

    const float4 w0 = W4[4 * d4 + 0];
    const float4 w1 = W4[4 * d4 + 1];
    const float4 w2 = W4[4 * d4 + 2];
    const float4 w3 = W4[4 * d4 + 3];
    const float4 bv = b4[d4];

    for (; f < N4; f += stride) {
        const int bt = (int)(f >> btShift);
        const v4f y = tfe_row(x4[bt], w0, w1, w2, w3, bv);
        __builtin_nontemporal_store(y, &out4[f]);
    }
}

// Fallback for non-pow2 S: block-per-(b,t) kernel.
__global__ __launch_bounds__(256) void tfe_embed_bcast(
    const float* __restrict__ x, const float* __restrict__ W,
    const float* __restrict__ bias, float* __restrict__ out, int S)
{
    const int bt = blockIdx.x;
    const int tid = threadIdx.x;
    const int d4 = tid & 127;
    const int shalf = tid >> 7;
    const float4 xv = ((const float4*)x)[bt];
    const float4* Wv = (const float4*)W;
    const float4 w0 = Wv[4 * d4 + 0];
    const float4 w1 = Wv[4 * d4 + 1];
    const float4 w2 = Wv[4 * d4 + 2];
    const float4 w3 = Wv[4 * d4 + 3];
    const float4 bv = ((const float4*)bias)[d4];
    const v4f y = tfe_row(xv, w0, w1, w2, w3, bv);
    v4f* orow = (v4f*)out + (size_t)bt * (size_t)S * 128;
    for (int si = shalf; si < S; si += 2)
        __builtin_nontemporal_store(y, &orow[(size_t)si * 128 + d4]);
}

extern "C" void kernel_launch(void* const* d_in, const int* in_sizes, int n_in,
                              void* d_out, int out_size, void* d_ws, size_t ws_size,
                              hipStream_t stream) {
    const float* x    = (const float*)d_in[0];   // [B,T,4] fp32
    const float* W    = (const float*)d_in[2];   // [512,4] fp32
    const float* bias = (const float*)d_in[3];   // [512]   fp32
    float* out        = (float*)d_out;

    const int BT = in_sizes[0] / D_INP;               // 3072 (sizes in elements)
    const int S  = out_size / (BT * D_MODEL);         // 64
    const size_t N4 = (size_t)out_size / 4;           // float4 count

    if ((S & (S - 1)) == 0) {
        // btShift = log2(S * 128): S=64 -> 13
        int btShift = 0, v = S * (D_MODEL / 4);
        while ((1 << (btShift + 1)) <= v) ++btShift;

        const int G = 256, B = 256;                   // 1 block/CU, 4 waves/CU
        const size_t stride = (size_t)G * B;          // 65536 float4 = 1 MB
        const size_t row = (size_t)S * (D_MODEL / 4); // float4 per bt (8192)
        const size_t niter = (stride && N4 >= stride) ? N4 / stride : 0;

        if (niter >= 1 && niter <= 1536 &&
            (N4 % stride) == 0 &&                     // all threads run niter iters
            (stride % row) == 0 &&                    // (s,d4) invariant, btStep exact
            (row % (size_t)B) == 0) {                 // bt0 block-uniform
            tfe_flat_lds_nt<<<G, B, 0, stream>>>(
                (const float4*)x, (const float4*)W, (const float4*)bias,
                (v4f*)out, btShift, (int)niter);
        } else {
            tfe_flat<<<2048, B, 0, stream>>>(
                (const float4*)x, (const float4*)W, (const float4*)bias,
                (v4f*)out, N4, btShift);
        }
    } else {
        tfe_embed_bcast<<<BT, 256, 0, stream>>>(x, W, bias, out, S);
    }
}